// Round 3
// baseline (252.494 us; speedup 1.0000x reference)
//
#include <hip/hip_runtime.h>
#include <hip/hip_bf16.h>

// Isokawa quaternion layer as bf16-MFMA GEMM:
//   out[b, n*4+oc] = sigmoid( sum_k x[b,k] * C[k, n*4+oc] - theta[n*4+oc] )
// B=131072 rows, K=256, N=256. Memory-bound: ~134 MB in + 134 MB out.
//
// R3: persistent pipelined blocks. Grid=512 (2 blocks/CU), 8 row-tiles each;
// next tile's x prefetched into registers during current tile's MFMA+epilogue
// so the HBM read stream overlaps compute and the write stream (R2 was
// phase-lockstepped: load/compute/store bursts never overlapped -> 2.2 TB/s).
// Wave tile = 64 rows x 16 cols -> breg = 8 frags = 32 VGPR (fits; R2's 64-reg
// slice got re-sunk into the loop, VGPR_Count=60 proved it).
// Barriers are raw lgkmcnt(0)+s_barrier: __syncthreads would vmcnt(0)-drain
// the prefetch loads right after issue.

typedef __bf16 bf16_t;
typedef bf16_t bf16x8 __attribute__((ext_vector_type(8)));
typedef bf16_t bf16x4v __attribute__((ext_vector_type(4)));
typedef float f32x4 __attribute__((ext_vector_type(4)));

#define B_TOTAL 131072
#define KDIM 256
#define NDIM 256
#define ROWS 64          // batch rows per tile
#define THREADS 512      // 8 waves
#define GRID 512         // 2 blocks/CU; bid>>8 = column half
#define TILES 8          // row-tiles per block (512*8 = 4096 = 2048 rows x 2 halves)
#define LDS_STRIDE 264   // bf16 elems per row: 256 + 8 pad

// ---------------------------------------------------------------------------
// Kernel 1: coefficient matrix in MFMA fragment order (bf16, in d_ws).
//   frag[((nt*8 + ks)*64 + lane)*8 + j] = Bmat[k][col]
//     col = nt*16 + (lane&15),  k = ks*32 + (lane>>4)*8 + j
// (Consumed as A-operand: A[m=lane&15][k=quad*8+j] with m = local col.)
// Bmat[k][col]: col = n*4+oc, k = m*4+ic,
//   value = sign[oc][ic] * W[n, m, widx[oc][ic]]  (Hamilton, W on the left)
// ---------------------------------------------------------------------------
__global__ void coef_kernel(const float* __restrict__ W, bf16_t* __restrict__ coef) {
    const int widx[4][4] = {{0,1,2,3},{1,0,3,2},{2,3,0,1},{3,2,1,0}};
    const float sgn[4][4] = {{1.f,-1.f,-1.f,-1.f},
                             {1.f, 1.f,-1.f, 1.f},
                             {1.f, 1.f, 1.f,-1.f},
                             {1.f,-1.f, 1.f, 1.f}};
    int F = blockIdx.x * blockDim.x + threadIdx.x;   // 0..65535
    int j    = F & 7;
    int lane = (F >> 3) & 63;
    int ks   = (F >> 9) & 7;
    int nt   = F >> 12;
    int col  = nt * 16 + (lane & 15);
    int k    = ks * 32 + (lane >> 4) * 8 + j;
    int n = col >> 2, oc = col & 3;
    int m = k >> 2,   ic = k & 3;
    coef[F] = (bf16_t)(sgn[oc][ic] * W[n * 256 + m * 4 + widx[oc][ic]]);
}

// Workgroup barrier WITHOUT vmcnt drain (only LDS ordering needed; in-flight
// global prefetch loads / epilogue stores must stay in flight).
__device__ __forceinline__ void wg_barrier() {
    asm volatile("s_waitcnt lgkmcnt(0)\n\ts_barrier" ::: "memory");
}

// ---------------------------------------------------------------------------
// Kernel 2: main GEMM. Block = 64 rows x 128 cols (one col-half); 8 waves,
// wave w owns col-tile nt = colhalf*8 + w (16 cols), all 64 rows.
// MFMA 16x16x32 bf16 (A=coef, B=x), verified layouts:
//   A: lane holds A[m=lane&15][k=(lane>>4)*8+j]      (m = local out-col)
//   B: lane holds B[k=(lane>>4)*8+j][n=lane&15]      (n = local batch row)
//   D: n=lane&15 (row), m=(lane>>4)*4+reg (col) -> 4 consecutive cols/lane
//      => float4 epilogue stores.
// ---------------------------------------------------------------------------
__global__ __launch_bounds__(THREADS, 4)
void main_kernel(const float* __restrict__ x, const bf16x8* __restrict__ coef,
                 const float* __restrict__ theta, float* __restrict__ out) {
    __shared__ __align__(16) bf16_t xs[ROWS * LDS_STRIDE];

    const int tid  = threadIdx.x;
    const int bid  = blockIdx.x;
    const int wave = tid >> 6, lane = tid & 63;
    const int l15  = lane & 15, quad = lane >> 4;
    const int colhalf = bid >> 8;            // 0 or 1
    const int rowblk  = bid & 255;           // 0..255
    const int nt   = colhalf * 8 + wave;     // col-tile 0..15
    const int col0 = nt * 16 + quad * 4;     // this lane's 4 output cols

    // --- prefetch x tile 0 (HBM: issue first)
    const float4* xp = (const float4*)(x + (size_t)rowblk * ROWS * KDIM);
    float4 v[8];
#pragma unroll
    for (int i = 0; i < 8; i++) v[i] = xp[tid + THREADS * i];

    // --- this wave's coef slice: 8 fragments = 32 VGPR, resident all tiles
    bf16x8 breg[8];
#pragma unroll
    for (int ks = 0; ks < 8; ks++)
        breg[ks] = coef[(nt * 8 + ks) * 64 + lane];

    const float4 th = *(const float4*)&theta[col0];

    for (int t = 0; t < TILES; t++) {
        const size_t row0 = (size_t)(rowblk + 256 * t) * ROWS;

        wg_barrier();                        // xs free (prev readers done)
        // stage v -> xs, fp32 -> bf16
#pragma unroll
        for (int i = 0; i < 8; i++) {
            int f = tid + THREADS * i;       // float4 index in 64x256 tile
            int r = f >> 6;
            int c = (f & 63) * 4;
            bf16x4v w;
            w.x = (bf16_t)v[i].x; w.y = (bf16_t)v[i].y;
            w.z = (bf16_t)v[i].z; w.w = (bf16_t)v[i].w;
            *(bf16x4v*)&xs[r * LDS_STRIDE + c] = w;
        }
        // prefetch next tile's x; stays in flight across the whole compute
        if (t + 1 < TILES) {
            const float4* xn = (const float4*)(x + (size_t)(rowblk + 256 * (t + 1)) * ROWS * KDIM);
#pragma unroll
            for (int i = 0; i < 8; i++) v[i] = xn[tid + THREADS * i];
        }
        wg_barrier();                        // xs ready

        f32x4 acc[4];
#pragma unroll
        for (int rt = 0; rt < 4; rt++) acc[rt] = (f32x4)(0.f);

#pragma unroll
        for (int ks = 0; ks < 8; ks++)
#pragma unroll
            for (int rt = 0; rt < 4; rt++) {
                bf16x8 xf = *(const bf16x8*)
                    &xs[(rt * 16 + l15) * LDS_STRIDE + ks * 32 + quad * 8];
                acc[rt] = __builtin_amdgcn_mfma_f32_16x16x32_bf16(
                    breg[ks], xf, acc[rt], 0, 0, 0);
            }

        // --- epilogue: bias + sigmoid, float4 stores
#pragma unroll
        for (int rt = 0; rt < 4; rt++) {
            size_t row = row0 + rt * 16 + l15;
            float4 y;
            y.x = __builtin_amdgcn_rcpf(1.f + __expf(-(acc[rt][0] - th.x)));
            y.y = __builtin_amdgcn_rcpf(1.f + __expf(-(acc[rt][1] - th.y)));
            y.z = __builtin_amdgcn_rcpf(1.f + __expf(-(acc[rt][2] - th.z)));
            y.w = __builtin_amdgcn_rcpf(1.f + __expf(-(acc[rt][3] - th.w)));
            *(float4*)&out[row * NDIM + col0] = y;
        }
    }
}

extern "C" void kernel_launch(void* const* d_in, const int* in_sizes, int n_in,
                              void* d_out, int out_size, void* d_ws, size_t ws_size,
                              hipStream_t stream) {
    const float* x     = (const float*)d_in[0];   // (131072, 64, 4) fp32
    const float* W     = (const float*)d_in[1];   // (64, 64, 4) fp32
    const float* theta = (const float*)d_in[2];   // (64, 4) fp32
    float* out = (float*)d_out;                   // (131072, 64, 4) fp32
    bf16_t* coef = (bf16_t*)d_ws;                 // 65536 bf16 = 128 KB

    if (ws_size < 65536 * sizeof(bf16_t)) return;

    coef_kernel<<<256, 256, 0, stream>>>(W, coef);
    main_kernel<<<GRID, THREADS, 0, stream>>>(
        x, (const bf16x8*)coef, theta, out);
}